// Round 8
// baseline (290.260 us; speedup 1.0000x reference)
//
#include <hip/hip_runtime.h>
#include <math.h>

#define EMBED    256
#define HIDDEN   512
#define KDIM     512
#define Nn       2000
#define Ee       2000
#define BM       128     // edges per block
#define NTHREADS 512     // 8 waves = 4 edge-groups x 2 n-halves, free-running
#define NBLK     2000    // 2000 * 128 = 256000 edges

typedef __attribute__((ext_vector_type(8)))  short bf16x8;
typedef __attribute__((ext_vector_type(16))) float f32x16;

static __device__ __forceinline__ short f2bf(float f) {
  unsigned u = __builtin_bit_cast(unsigned, f);
  u += 0x7fffu + ((u >> 16) & 1u);
  return (short)(u >> 16);
}

static __device__ __forceinline__ bf16x8 cvt8(float4 a, float4 b) {
  bf16x8 v;
  v[0]=f2bf(a.x); v[1]=f2bf(a.y); v[2]=f2bf(a.z); v[3]=f2bf(a.w);
  v[4]=f2bf(b.x); v[5]=f2bf(b.y); v[6]=f2bf(b.z); v[7]=f2bf(b.w);
  return v;
}

// ---- prep: W1 (513x512 f32 [k][n]) -> fragment-major W1F bf16 ----
// W1F[((tn*32 + tk)*64 + lane)*8 + q] = W1[tk*16 + (lane>>5)*8 + q][tn*32 + (lane&31)]
__global__ void w1f_kernel(const float* __restrict__ W1, short* __restrict__ W1F) {
  const int t  = blockIdx.x * 512 + threadIdx.x;   // 32768 fragment-lanes
  const int l  = t & 63;
  const int tk = (t >> 6) & 31;
  const int tn = t >> 11;
  const int n  = tn * 32 + (l & 31);
  const int k0 = tk * 16 + (l >> 5) * 8;
  bf16x8 v;
#pragma unroll
  for (int q = 0; q < 8; ++q)
    v[q] = f2bf(W1[(size_t)(k0 + q) * HIDDEN + n]);
  *(bf16x8*)(W1F + (size_t)t * 8) = v;
}

// ---- main fused kernel: barrier-free waves, register-direct B fragments ----
__global__ __launch_bounds__(NTHREADS, 2)
void edge_kernel(const float* __restrict__ emb, const float* __restrict__ locs,
                 const int* __restrict__ edges, const int* __restrict__ dbias,
                 const float* __restrict__ W1, const float* __restrict__ b1,
                 const float* __restrict__ W2, const float* __restrict__ b2,
                 const short* __restrict__ W1F, float* __restrict__ out)
{
  __shared__ float4 ep_s[HIDDEN];     // 8 KB {b1, W1[512][n], W2, 0}
  __shared__ float  part_s[8][32];    // 1 KB n-half join

  const int tid = threadIdx.x;

  // bijective XCD-chunked swizzle: 2000 = 8 * 250
  const int wg = (blockIdx.x & 7) * (NBLK / 8) + (blockIdx.x >> 3);

  const int lane  = tid & 63;
  const int w     = tid >> 6;     // wave 0..7
  const int eg    = w & 3;        // edge-group: edges [eg*32, +32)
  const int nhalf = w >> 2;       // hidden half: n in [nhalf*256, +256)
  const int ln31  = lane & 31;
  const int kg    = lane >> 5;

  // ---- per-lane meta for OWN edge (lanes l and l+32 share an edge) ----
  const int g  = wg * BM + eg * 32 + ln31;
  const int b  = g / Ee;
  const int i0 = edges[2 * g];
  const int j0 = edges[2 * g + 1];
  const int valid = (i0 >= 0) && (j0 >= 0);
  const float* pi = emb + (size_t)(b * Nn + (i0 < 0 ? 0 : i0)) * EMBED;
  const float* pj = emb + (size_t)(b * Nn + (j0 < 0 ? 0 : j0)) * EMBED;
  const float dx = pi == pj ? 0.f :
      (locs[2 * (size_t)(b * Nn + (i0 < 0 ? 0 : i0))]     - locs[2 * (size_t)(b * Nn + (j0 < 0 ? 0 : j0))]);
  const float dy = pi == pj ? 0.f :
      (locs[2 * (size_t)(b * Nn + (i0 < 0 ? 0 : i0)) + 1] - locs[2 * (size_t)(b * Nn + (j0 < 0 ? 0 : j0)) + 1]);
  const float dist = sqrtf(dx * dx + dy * dy);

  ep_s[tid] = make_float4(b1[tid], W1[(size_t)KDIM * HIDDEN + tid], W2[tid], 0.f);
  __syncthreads();     // the ONLY barrier before the join

  f32x16 acc[8];
#pragma unroll
  for (int nt = 0; nt < 8; ++nt)
#pragma unroll
    for (int q = 0; q < 16; ++q) acc[nt][q] = 0.f;

  // ---- prologue: gather chunk 0 fragments (own edge, f32) ----
  float4 gr[8];
#pragma unroll
  for (int ks = 0; ks < 4; ++ks) {
    gr[2 * ks]     = *(const float4*)(pi + ks * 16 + kg * 8);
    gr[2 * ks + 1] = *(const float4*)(pi + ks * 16 + kg * 8 + 4);
  }

  // ---- K loop: 8 chunks of 64, NO barriers, waves free-run ----
#pragma unroll 1
  for (int c = 0; c < 8; ++c) {
    // convert held gathers to this chunk's B fragments (frees gr)
    bf16x8 fbb[4];
#pragma unroll
    for (int ks = 0; ks < 4; ++ks) fbb[ks] = cvt8(gr[2 * ks], gr[2 * ks + 1]);

#pragma unroll
    for (int ks = 0; ks < 4; ++ks) {
      bf16x8 wa[8];
#pragma unroll
      for (int nt = 0; nt < 8; ++nt)
        wa[nt] = *(const bf16x8*)(W1F +
            ((size_t)((nhalf * 8 + nt) * 32 + c * 4 + ks)) * 512 + lane * 8);

      if (ks == 3) {
        // issue next-chunk gather AFTER this ks's wa loads (so wa's counted
        // vmcnt wait spares it) and BEFORE the MFMAs (max flight time)
        __builtin_amdgcn_sched_barrier(0);
        if (c < 7) {
          const float* pn = ((c + 1) < 4 ? pi : pj) + ((c + 1) & 3) * 64 + kg * 8;
#pragma unroll
          for (int s2 = 0; s2 < 4; ++s2) {
            gr[2 * s2]     = *(const float4*)(pn + s2 * 16);
            gr[2 * s2 + 1] = *(const float4*)(pn + s2 * 16 + 4);
          }
        }
        __builtin_amdgcn_sched_barrier(0);
      }

#pragma unroll
      for (int nt = 0; nt < 8; ++nt)
        acc[nt] = __builtin_amdgcn_mfma_f32_32x32x16_bf16(wa[nt], fbb[ks], acc[nt], 0, 0, 0);
    }
  }

  // ---- epilogue: dist col + bias + relu + in-lane W2 dot over 256 n ----
  float ps = 0.f;
#pragma unroll
  for (int nt = 0; nt < 8; ++nt) {
#pragma unroll
    for (int r = 0; r < 16; ++r) {
      const int n = nhalf * 256 + nt * 32 + (r & 3) + ((r >> 2) << 3) + (kg << 2);
      const float4 ep = ep_s[n];
      float p = acc[nt][r] + ep.x + dist * ep.y;
      ps += fmaxf(p, 0.f) * ep.z;
    }
  }
  ps += __shfl_xor(ps, 32, 64);          // fold kg halves (rows +4)
  if (lane < 32) part_s[w][ln31] = ps;
  __syncthreads();

  if (tid < BM) {
    const int e = tid;
    float s = part_s[e >> 5][e & 31] + part_s[4 + (e >> 5)][e & 31];
    float logit = s + b2[0] + (float)dbias[0];
    // recompute valid for this thread's edge
    const int gg = wg * BM + e;
    const int ii = edges[2 * gg], jj = edges[2 * gg + 1];
    if (!((ii >= 0) && (jj >= 0))) logit = -__builtin_inff();
    out[(size_t)wg * BM + e] = logit;
  }
}

extern "C" void kernel_launch(void* const* d_in, const int* in_sizes, int n_in,
                              void* d_out, int out_size, void* d_ws, size_t ws_size,
                              hipStream_t stream) {
  const float* emb   = (const float*)d_in[0];
  const float* locs  = (const float*)d_in[1];
  const int*   edges = (const int*)d_in[2];
  const int*   dbias = (const int*)d_in[3];
  const float* W1    = (const float*)d_in[4];
  const float* b1    = (const float*)d_in[5];
  const float* W2    = (const float*)d_in[6];
  const float* b2    = (const float*)d_in[7];
  float*       out   = (float*)d_out;
  short*       W1F   = (short*)d_ws;   // 512*512*2 = 512 KiB fragment-major

  w1f_kernel<<<dim3(64), dim3(512), 0, stream>>>(W1, W1F);
  edge_kernel<<<dim3(NBLK), dim3(NTHREADS), 0, stream>>>(
      emb, locs, edges, dbias, W1, b1, W2, b2, (const short*)W1F, out);
}

// Round 9
// 198.014 us; speedup vs baseline: 1.4659x; 1.4659x over previous
//
#include <hip/hip_runtime.h>
#include <math.h>

#define EMBED    256
#define HIDDEN   512
#define Nn       2000
#define Ee       2000
#define BM       128     // edges per block
#define NTHREADS 512     // 8 waves, each owns 64-n slice x all 128 edges
#define NBLK     2000    // 2000 * 128 = 256000 edges
#define KSTEPS   16      // k-steps of 16 per phase (phase = 256 k)

typedef __attribute__((ext_vector_type(8)))  short bf16x8;
typedef __attribute__((ext_vector_type(16))) float f32x16;

static __device__ __forceinline__ short f2bf(float f) {
  unsigned u = __builtin_bit_cast(unsigned, f);
  u += 0x7fffu + ((u >> 16) & 1u);
  return (short)(u >> 16);
}

static __device__ __forceinline__ bf16x8 cvt8(float4 a, float4 b) {
  bf16x8 v;
  v[0]=f2bf(a.x); v[1]=f2bf(a.y); v[2]=f2bf(a.z); v[3]=f2bf(a.w);
  v[4]=f2bf(b.x); v[5]=f2bf(b.y); v[6]=f2bf(b.z); v[7]=f2bf(b.w);
  return v;
}

// ---- prep: W1 (513x512 f32 [k][n]) -> fragment-major W1F bf16 ----
// W1F[((tn*32 + tk)*64 + lane)*8 + q] = W1[tk*16 + (lane>>5)*8 + q][tn*32 + (lane&31)]
__global__ void w1f_kernel(const float* __restrict__ W1, short* __restrict__ W1F) {
  const int t  = blockIdx.x * 512 + threadIdx.x;   // 32768 fragment-lanes
  const int l  = t & 63;
  const int tk = (t >> 6) & 31;
  const int tn = t >> 11;
  const int n  = tn * 32 + (l & 31);
  const int k0 = tk * 16 + (l >> 5) * 8;
  bf16x8 v;
#pragma unroll
  for (int q = 0; q < 8; ++q)
    v[q] = f2bf(W1[(size_t)(k0 + q) * HIDDEN + n]);
  *(bf16x8*)(W1F + (size_t)t * 8) = v;
}

// ---- main: 2 phases (emb_i, emb_j); fragment-major LDS; barrier-free compute ----
__global__ __launch_bounds__(NTHREADS, 2)
void edge_kernel(const float* __restrict__ emb, const float* __restrict__ locs,
                 const int* __restrict__ edges, const int* __restrict__ dbias,
                 const float* __restrict__ W1, const float* __restrict__ b1,
                 const float* __restrict__ W2, const float* __restrict__ b2,
                 const short* __restrict__ W1F, float* __restrict__ out)
{
  // fragment-major feats: ffrag[ks 0..15][et 0..3][slot 0..63] of bf16x8
  __shared__ short ffrag[KSTEPS * 4 * 64 * 8];    // 65,536 B
  __shared__ float b1_s[HIDDEN], w513_s[HIDDEN], w2_s[HIDDEN];  // 6 KB
  __shared__ float part_s[8][BM];                 // 4 KB
  __shared__ float dist_s[BM];
  __shared__ int   valid_s[BM], ibase_s[BM], jbase_s[BM];   // ~2 KB  (total ~78 KB)

  const int tid = threadIdx.x;

  // bijective XCD-chunked swizzle: 2000 = 8 * 250
  const int wg = (blockIdx.x & 7) * (NBLK / 8) + (blockIdx.x >> 3);

  // ---- meta + epilogue tables ----
  if (tid < BM) {
    const int g  = wg * BM + tid;
    const int b  = g / Ee;
    const int i0 = edges[2 * g];
    const int j0 = edges[2 * g + 1];
    valid_s[tid] = (i0 >= 0) && (j0 >= 0);
    const int ib = b * Nn + (i0 < 0 ? 0 : i0);
    const int jb = b * Nn + (j0 < 0 ? 0 : j0);
    ibase_s[tid] = ib;
    jbase_s[tid] = jb;
    const float dx = locs[2 * (size_t)ib]     - locs[2 * (size_t)jb];
    const float dy = locs[2 * (size_t)ib + 1] - locs[2 * (size_t)jb + 1];
    dist_s[tid] = sqrtf(dx * dx + dy * dy);
  }
  b1_s[tid]   = b1[tid];
  w513_s[tid] = W1[(size_t)512 * HIDDEN + tid];
  w2_s[tid]   = W2[tid];
  __syncthreads();

  // staging map: 4 threads per edge, each covers 64 floats of the phase-row
  const int e  = tid >> 2;     // edge 0..127
  const int sq = tid & 3;      // k quarter

  const int lane = tid & 63;
  const int w    = tid >> 6;   // wave 0..7 -> n-slice [w*64, +64)
  const int ln31 = lane & 31;
  const int kg   = lane >> 5;

  const float* rowi = emb + (size_t)ibase_s[e] * EMBED + sq * 64;
  const float* rowj = emb + (size_t)jbase_s[e] * EMBED + sq * 64;

  f32x16 acc[4][2];            // [edge-tile et][n-tile nt]
#pragma unroll
  for (int et = 0; et < 4; ++et)
#pragma unroll
    for (int nt = 0; nt < 2; ++nt)
#pragma unroll
      for (int q = 0; q < 16; ++q) acc[et][nt][q] = 0.f;

#pragma unroll 1
  for (int ph = 0; ph < 2; ++ph) {
    // ---- stage phase (256 k of i- or j-embeddings), fragment-major ----
    {
      const float* src = ph == 0 ? rowi : rowj;
      const int et = e >> 5;
      const int es = e & 31;
#pragma unroll
      for (int gph = 0; gph < 2; ++gph) {
        float4 t[8];
#pragma unroll
        for (int q = 0; q < 8; ++q) t[q] = *(const float4*)(src + gph * 32 + 4 * q);
#pragma unroll
        for (int p = 0; p < 4; ++p) {
          const int j  = gph * 4 + p;            // 8-float chunk id (k = j*8)
          const int ks = sq * 4 + (j >> 1);
          const int dst16 = ((ks * 4 + et) * 64 + (j & 1) * 32 + es);
          *(bf16x8*)&ffrag[dst16 * 8] = cvt8(t[2 * p], t[2 * p + 1]);
        }
      }
    }
    __syncthreads();

    // ---- compute: 16 k-steps, NO barriers, waves free-run ----
    // wa (nt,ks) at W1F + ((w*2+nt)*32 + ph*16 + ks)*512 + lane*8
    const short* wb = W1F + ((size_t)(w * 2) * 32 + ph * 16) * 512 + lane * 8;
    bf16x8 wc0 = *(const bf16x8*)(wb);
    bf16x8 wc1 = *(const bf16x8*)(wb + 32 * 512);
#pragma unroll
    for (int ks = 0; ks < KSTEPS; ++ks) {
      bf16x8 wn0, wn1;
      if (ks < KSTEPS - 1) {
        wn0 = *(const bf16x8*)(wb + (ks + 1) * 512);
        wn1 = *(const bf16x8*)(wb + 32 * 512 + (ks + 1) * 512);
      }
#pragma unroll
      for (int et = 0; et < 4; ++et) {
        bf16x8 fb = *(const bf16x8*)(&ffrag[((ks * 4 + et) * 64 + lane) * 8]);
        acc[et][0] = __builtin_amdgcn_mfma_f32_32x32x16_bf16(wc0, fb, acc[et][0], 0, 0, 0);
        acc[et][1] = __builtin_amdgcn_mfma_f32_32x32x16_bf16(wc1, fb, acc[et][1], 0, 0, 0);
      }
      wc0 = wn0; wc1 = wn1;
    }
    __syncthreads();   // ffrag consumed; safe to restage (ph=0) / fall through
  }

  // ---- epilogue: dist col + bias + relu + in-lane W2 dot over wave's 64 n ----
  float dv[4], ps[4];
#pragma unroll
  for (int et = 0; et < 4; ++et) {
    dv[et] = dist_s[et * 32 + ln31];
    ps[et] = 0.f;
  }
#pragma unroll
  for (int nt = 0; nt < 2; ++nt) {
#pragma unroll
    for (int r = 0; r < 16; ++r) {
      const int n = w * 64 + nt * 32 + (r & 3) + ((r >> 2) << 3) + (kg << 2);
      const float bias = b1_s[n];
      const float wd   = w513_s[n];
      const float w2v  = w2_s[n];
#pragma unroll
      for (int et = 0; et < 4; ++et) {
        float p = acc[et][nt][r] + bias + dv[et] * wd;
        ps[et] += fmaxf(p, 0.f) * w2v;
      }
    }
  }
#pragma unroll
  for (int et = 0; et < 4; ++et) ps[et] += __shfl_xor(ps[et], 32, 64);
  if (lane < 32) {
#pragma unroll
    for (int et = 0; et < 4; ++et) part_s[w][et * 32 + ln31] = ps[et];
  }
  __syncthreads();

  if (tid < BM) {
    float s = 0.f;
#pragma unroll
    for (int wv = 0; wv < 8; ++wv) s += part_s[wv][tid];
    float logit = s + b2[0] + (float)dbias[0];
    if (!valid_s[tid]) logit = -__builtin_inff();
    out[(size_t)wg * BM + tid] = logit;
  }
}

extern "C" void kernel_launch(void* const* d_in, const int* in_sizes, int n_in,
                              void* d_out, int out_size, void* d_ws, size_t ws_size,
                              hipStream_t stream) {
  const float* emb   = (const float*)d_in[0];
  const float* locs  = (const float*)d_in[1];
  const int*   edges = (const int*)d_in[2];
  const int*   dbias = (const int*)d_in[3];
  const float* W1    = (const float*)d_in[4];
  const float* b1    = (const float*)d_in[5];
  const float* W2    = (const float*)d_in[6];
  const float* b2    = (const float*)d_in[7];
  float*       out   = (float*)d_out;
  short*       W1F   = (short*)d_ws;   // 512*512*2 = 512 KiB fragment-major

  w1f_kernel<<<dim3(64), dim3(512), 0, stream>>>(W1, W1F);
  edge_kernel<<<dim3(NBLK), dim3(NTHREADS), 0, stream>>>(
      emb, locs, edges, dbias, W1, b1, W2, b2, (const short*)W1F, out);
}

// Round 10
// 151.714 us; speedup vs baseline: 1.9132x; 1.3052x over previous
//
#include <hip/hip_runtime.h>
#include <math.h>

#define EMBED    256
#define HIDDEN   512
#define Nn       2000
#define Ee       2000
#define BM       128     // edges per tile
#define TILES    8       // tiles per persistent block
#define NBLK     250     // 250 * 8 * 128 = 256000 edges
#define NTHREADS 512     // 8 waves, n-sliced (each wave: 64 n x 128 edges)
#define FP       264     // shorts per feat row (256 + 8 pad -> bank-rotating rows)

typedef __attribute__((ext_vector_type(8)))  short bf16x8;
typedef __attribute__((ext_vector_type(16))) float f32x16;

static __device__ __forceinline__ short f2bf(float f) {
  unsigned u = __builtin_bit_cast(unsigned, f);
  u += 0x7fffu + ((u >> 16) & 1u);
  return (short)(u >> 16);
}

static __device__ __forceinline__ bf16x8 cvt8(float4 a, float4 b) {
  bf16x8 v;
  v[0]=f2bf(a.x); v[1]=f2bf(a.y); v[2]=f2bf(a.z); v[3]=f2bf(a.w);
  v[4]=f2bf(b.x); v[5]=f2bf(b.y); v[6]=f2bf(b.z); v[7]=f2bf(b.w);
  return v;
}

#define LBAR() do { asm volatile("s_waitcnt lgkmcnt(0)" ::: "memory"); \
                    __builtin_amdgcn_s_barrier(); \
                    asm volatile("" ::: "memory"); } while (0)

// ---- prep: W1 (513x512 f32 [k][n]) -> fragment-major W1F bf16 ----
// W1F[((tn*32 + tk)*64 + lane)*8 + q] = W1[tk*16 + (lane>>5)*8 + q][tn*32 + (lane&31)]
__global__ void w1f_kernel(const float* __restrict__ W1, short* __restrict__ W1F) {
  const int t  = blockIdx.x * 512 + threadIdx.x;   // 32768 fragment-lanes
  const int l  = t & 63;
  const int tk = (t >> 6) & 31;
  const int tn = t >> 11;
  const int n  = tn * 32 + (l & 31);
  const int k0 = tk * 16 + (l >> 5) * 8;
  bf16x8 v;
#pragma unroll
  for (int q = 0; q < 8; ++q)
    v[q] = f2bf(W1[(size_t)(k0 + q) * HIDDEN + n]);
  *(bf16x8*)(W1F + (size_t)t * 8) = v;
}

// ---- main: persistent blocks, 17 phases, barrier-free 16-k-step compute ----
__global__ __launch_bounds__(NTHREADS, 2)
void edge_kernel(const float* __restrict__ emb, const float* __restrict__ locs,
                 const int* __restrict__ edges, const int* __restrict__ dbias,
                 const float* __restrict__ W1, const float* __restrict__ b1,
                 const float* __restrict__ W2, const float* __restrict__ b2,
                 const short* __restrict__ W1F, float* __restrict__ out)
{
  __shared__ short feat[2][BM][FP];               // 135,168 B
  __shared__ float b1_s[HIDDEN], w513_s[HIDDEN], w2_s[HIDDEN];  // 6 KB
  __shared__ float part_s[8][BM];                 // 4 KB
  __shared__ float dist_s[2][BM];                 // 1 KB
  __shared__ int   valid_s[2][BM];                // 1 KB
  __shared__ int   ibase_s[2][BM], jbase_s[2][BM];// 2 KB   total ~149.5 KB

  const int tid = threadIdx.x;

  // bijective XCD-chunked swizzle over 250 blocks (xcd 0,1 -> 32; 2..7 -> 31)
  const int orig = blockIdx.x;
  const int xcd  = orig & 7;
  const int idx  = orig >> 3;
  const int sbid = (xcd < 2 ? xcd * 32 : 64 + (xcd - 2) * 31) + idx;
  const int eblk = sbid * (TILES * BM);

  b1_s[tid]   = b1[tid];
  w513_s[tid] = W1[(size_t)512 * HIDDEN + tid];
  w2_s[tid]   = W2[tid];
  const float b2s_base = b2[0] + (float)dbias[0];

  auto do_meta = [&](int T) {     // tid < BM only
    const int g  = eblk + T * BM + tid;
    const int b  = g / Ee;
    const int i0 = edges[2 * g];
    const int j0 = edges[2 * g + 1];
    valid_s[T & 1][tid] = (i0 >= 0) && (j0 >= 0);
    const int ib = b * Nn + (i0 < 0 ? 0 : i0);
    const int jb = b * Nn + (j0 < 0 ? 0 : j0);
    ibase_s[T & 1][tid] = ib;
    jbase_s[T & 1][tid] = jb;
    const float dx = locs[2 * (size_t)ib]     - locs[2 * (size_t)jb];
    const float dy = locs[2 * (size_t)ib + 1] - locs[2 * (size_t)jb + 1];
    dist_s[T & 1][tid] = sqrtf(dx * dx + dy * dy);
  };

  if (tid < BM) do_meta(0);
  LBAR();

  // staging map: 8 threads/edge-row-half; thread covers 16B chunks c = sq+8m
  const int sq = tid & 7;
  const int eh = tid >> 3;        // 0..63 (edge within round)
  const int lane = tid & 63;
  const int w    = tid >> 6;      // wave 0..7 -> n-slice [w*64, +64)
  const int ln31 = lane & 31;
  const int kg   = lane >> 5;

  // ---- prologue: stage phase 0 = (tile0, emb_i) ----
#pragma unroll
  for (int r = 0; r < 2; ++r) {
    const int el = r * 64 + eh;
    const float* src = emb + (size_t)ibase_s[0][el] * EMBED + sq * 8;
#pragma unroll
    for (int m = 0; m < 4; ++m) {
      float4 a  = *(const float4*)(src + m * 64);
      float4 b4 = *(const float4*)(src + m * 64 + 4);
      *(bf16x8*)&feat[0][el][(sq + 8 * m) * 8] = cvt8(a, b4);
    }
  }
  LBAR();

  f32x16 acc[4][2];
#pragma unroll
  for (int et = 0; et < 4; ++et)
#pragma unroll
    for (int nt = 0; nt < 2; ++nt)
#pragma unroll
      for (int q = 0; q < 16; ++q) acc[et][nt][q] = 0.f;

  const short* wfb = W1F + (size_t)(w * 2 * 32) * 512 + lane * 8;  // + (nt*32+tk)*512

#pragma unroll 1
  for (int p = 0; p < 2 * TILES; ++p) {
    const int bb   = p & 1;
    const int nbuf = bb ^ 1;
    const int half = p & 1;            // k-half of W1 this phase covers
    const int tps  = (p + 1) >> 1;     // tile being staged
    const int sh   = (p + 1) & 1;      // 0 = emb_i, 1 = emb_j
    const bool stg = p < 2 * TILES - 1;

    bf16x8 wc0 = *(const bf16x8*)(wfb + (size_t)(half * 16) * 512);
    bf16x8 wc1 = *(const bf16x8*)(wfb + (size_t)(32 + half * 16) * 512);

    float4 hg00, hg01, hg10, hg11;     // held gather group (16 floats)

#pragma unroll
    for (int ks = 0; ks < 16; ++ks) {
      bf16x8 wn0, wn1;
      if (ks < 15) {
        wn0 = *(const bf16x8*)(wfb + (size_t)(half * 16 + ks + 1) * 512);
        wn1 = *(const bf16x8*)(wfb + (size_t)(32 + half * 16 + ks + 1) * 512);
      }

      if (stg && (ks & 3) == 0) {      // issue gather group ks>>2
        const int g2 = ks >> 2;
        const int el = (g2 >> 1) * 64 + eh;
        const int rb = sh ? jbase_s[tps & 1][el] : ibase_s[tps & 1][el];
        const float* src = emb + (size_t)rb * EMBED + sq * 8 + (g2 & 1) * 128;
        hg00 = *(const float4*)(src);
        hg01 = *(const float4*)(src + 4);
        hg10 = *(const float4*)(src + 64);
        hg11 = *(const float4*)(src + 68);
      }
      if (stg && (ks & 3) == 3) {      // land group ks>>2 into next buffer
        const int g2 = ks >> 2;
        const int el = (g2 >> 1) * 64 + eh;
        const int mb = (g2 & 1) * 2;
        *(bf16x8*)&feat[nbuf][el][(sq + 8 * mb) * 8]       = cvt8(hg00, hg01);
        *(bf16x8*)&feat[nbuf][el][(sq + 8 * (mb + 1)) * 8] = cvt8(hg10, hg11);
      }
      if ((p & 1) == 0 && ks == 1 && tid < BM && (p >> 1) + 1 < TILES)
        do_meta((p >> 1) + 1);

#pragma unroll
      for (int et = 0; et < 4; ++et) {
        bf16x8 fb = *(const bf16x8*)(&feat[bb][et * 32 + ln31][ks * 16 + kg * 8]);
        acc[et][0] = __builtin_amdgcn_mfma_f32_32x32x16_bf16(wc0, fb, acc[et][0], 0, 0, 0);
        acc[et][1] = __builtin_amdgcn_mfma_f32_32x32x16_bf16(wc1, fb, acc[et][1], 0, 0, 0);
      }
      wc0 = wn0; wc1 = wn1;
    }
    LBAR();   // next buffer staged + current buffer free

    if (p & 1) {
      // ---- epilogue for tile t = p>>1 ----
      const int t   = p >> 1;
      const int mb2 = t & 1;
      float dv[4], ps[4];
#pragma unroll
      for (int et = 0; et < 4; ++et) {
        dv[et] = dist_s[mb2][et * 32 + ln31];
        ps[et] = 0.f;
      }
#pragma unroll
      for (int nt = 0; nt < 2; ++nt) {
#pragma unroll
        for (int r = 0; r < 16; ++r) {
          const int n = w * 64 + nt * 32 + (r & 3) + ((r >> 2) << 3) + (kg << 2);
          const float bias = b1_s[n];
          const float wd   = w513_s[n];
          const float w2v  = w2_s[n];
#pragma unroll
          for (int et = 0; et < 4; ++et) {
            float pv = acc[et][nt][r] + bias + dv[et] * wd;
            ps[et] += fmaxf(pv, 0.f) * w2v;
          }
        }
      }
#pragma unroll
      for (int et = 0; et < 4; ++et) ps[et] += __shfl_xor(ps[et], 32, 64);
      if (lane < 32) {
#pragma unroll
        for (int et = 0; et < 4; ++et) part_s[w][et * 32 + ln31] = ps[et];
      }
      LBAR();
      if (tid < BM) {
        float s = 0.f;
#pragma unroll
        for (int wv = 0; wv < 8; ++wv) s += part_s[wv][tid];
        float logit = s + b2s_base;
        if (!valid_s[mb2][tid]) logit = -__builtin_inff();
        out[eblk + t * BM + tid] = logit;
      }
      // reset accumulators for next tile
#pragma unroll
      for (int et = 0; et < 4; ++et)
#pragma unroll
        for (int nt = 0; nt < 2; ++nt)
#pragma unroll
          for (int q = 0; q < 16; ++q) acc[et][nt][q] = 0.f;
    }
  }
}

extern "C" void kernel_launch(void* const* d_in, const int* in_sizes, int n_in,
                              void* d_out, int out_size, void* d_ws, size_t ws_size,
                              hipStream_t stream) {
  const float* emb   = (const float*)d_in[0];
  const float* locs  = (const float*)d_in[1];
  const int*   edges = (const int*)d_in[2];
  const int*   dbias = (const int*)d_in[3];
  const float* W1    = (const float*)d_in[4];
  const float* b1    = (const float*)d_in[5];
  const float* W2    = (const float*)d_in[6];
  const float* b2    = (const float*)d_in[7];
  float*       out   = (float*)d_out;
  short*       W1F   = (short*)d_ws;   // 512*512*2 = 512 KiB fragment-major

  w1f_kernel<<<dim3(64), dim3(512), 0, stream>>>(W1, W1F);
  edge_kernel<<<dim3(NBLK), dim3(NTHREADS), 0, stream>>>(
      emb, locs, edges, dbias, W1, b1, W2, b2, (const short*)W1F, out);
}